// Round 7
// baseline (381.355 us; speedup 1.0000x reference)
//
#include <hip/hip_runtime.h>
#include <hip/hip_bf16.h>

typedef short bf16x8 __attribute__((ext_vector_type(8)));
typedef float f32x4 __attribute__((ext_vector_type(4)));

#define NB 16384
#define IN_DIM 512
#define HD 1024
#define NT 512
#define KTILES 48   // 32-k subtiles per strip
#define KT64 24     // 64-k K-tiles per output tile

__device__ __forceinline__ short f2b(float f) {
    __hip_bfloat16 h = __float2bfloat16(f);
    return *reinterpret_cast<short*>(&h);
}

__device__ __forceinline__ void gload16(const void* g, void* l) {
    __builtin_amdgcn_global_load_lds(
        (const __attribute__((address_space(1))) void*)g,
        (__attribute__((address_space(3))) void*)l, 16, 0, 0);
}

__device__ __forceinline__ float fexp(float x)  { return __expf(x); }
__device__ __forceinline__ float frcp(float x)  { return __builtin_amdgcn_rcpf(x); }

// ---------------- prepass: weights -> bf16 swizzled tiles (verified) ---------
__global__ void prep_w(const float* __restrict__ w_w, const float* __restrict__ r_w,
                       short* __restrict__ wsB) {
    const int blk = blockIdx.x;          // bh*48 + kt
    const int kt  = blk % KTILES;
    const int cid = threadIdx.x;         // 0..255
    const int bh  = blk / KTILES;
    const int g   = (cid >> 4) & 3;
    const int jh  = ((cid >> 6) << 4) | (cid & 15);
    const int gcol = g * HD + bh * 64 + jh;

    const float* src = (kt < 16) ? w_w : r_w;
    const int kbase  = (kt < 16) ? kt * 32 : (kt - 16) * 32;

    float v[32];
#pragma unroll
    for (int kk = 0; kk < 32; ++kk)
        v[kk] = src[(size_t)(kbase + kk) * 4096 + gcol];

    char* tile = (char*)(wsB + (size_t)blk * 8192);
    const int swz = ((cid >> 1) & 3) << 4;
#pragma unroll
    for (int s = 0; s < 4; ++s) {
        bf16x8 o;
#pragma unroll
        for (int j = 0; j < 8; ++j) o[j] = f2b(v[s * 8 + j]);
        *(bf16x8*)(tile + cid * 64 + ((s * 16) ^ swz)) = o;
    }
}

// ---------------- prepass: activations -> bf16 swizzled tiles (verified) -----
__global__ void prep_a(const float* __restrict__ x, const float* __restrict__ h_p,
                       short* __restrict__ wsA) {
    const int blk  = blockIdx.x;         // bm*48 + kt
    const int kt   = blk % KTILES;
    const int bm   = blk / KTILES;
    const int t    = threadIdx.x;        // 0..511
    const int row  = t >> 1;             // 0..255
    const int half = t & 1;
    const int grow = bm * 256 + row;

    const float* src = (kt < 16)
        ? x   + (size_t)grow * IN_DIM + kt * 32 + half * 16
        : h_p + (size_t)grow * HD     + (kt - 16) * 32 + half * 16;

    float4 a0 = ((const float4*)src)[0];
    float4 a1 = ((const float4*)src)[1];
    float4 a2 = ((const float4*)src)[2];
    float4 a3 = ((const float4*)src)[3];
    float v[16] = {a0.x,a0.y,a0.z,a0.w, a1.x,a1.y,a1.z,a1.w,
                   a2.x,a2.y,a2.z,a2.w, a3.x,a3.y,a3.z,a3.w};

    char* tile = (char*)(wsA + (size_t)blk * 8192);
    const int swz = ((row >> 1) & 3) << 4;
#pragma unroll
    for (int s = 0; s < 2; ++s) {
        bf16x8 o;
#pragma unroll
        for (int j = 0; j < 8; ++j) o[j] = f2b(v[s * 8 + j]);
        *(bf16x8*)(tile + row * 64 + ((half * 32 + s * 16) ^ swz)) = o;
    }
}

// ---------------- main: 8-phase fine-interleave K-loop ----------------------
// LDS slot layout (shorts, per slot of 32768): A0=0, A1=8192, B0=16384, B1=24576
template<int H>
__device__ __forceinline__ void mq(const bf16x8 (&af)[4], const bf16x8 (&bfr)[4],
                                   f32x4 (&acc)[8][4]) {
    __builtin_amdgcn_s_setprio(1);
#pragma unroll
    for (int mi = 0; mi < 4; ++mi)
#pragma unroll
        for (int g = 0; g < 4; ++g)
            acc[H + mi][g] = __builtin_amdgcn_mfma_f32_16x16x32_bf16(
                af[mi], bfr[g], acc[H + mi][g], 0, 0, 0);
    __builtin_amdgcn_s_setprio(0);
}

template<int N>
__device__ __forceinline__ void waitvm() {
    if constexpr (N == 4) asm volatile("s_waitcnt vmcnt(4)" ::: "memory");
    else                  asm volatile("s_waitcnt vmcnt(0)" ::: "memory");
}

// One K=64 tile: 4 phases, each {ds_reads, 1 stage-unit, bar, 16 MFMA, bar}.
template<int CS, bool STG, int VMW>
__device__ __forceinline__ void ktile(const short* sA, const short* sB,
                                      short (*S)[32768], int aoff, int boff,
                                      int wid, f32x4 (&acc)[8][4]) {
    const short* Sc = S[CS];
    short*       Sd = S[CS ^ 1];
    bf16x8 bfr[4], af[4];

    // P0: reads B0 + A0(mi0-3); stage A0'
#pragma unroll
    for (int g = 0; g < 4; ++g)    bfr[g] = *(const bf16x8*)&Sc[16384 + boff + g * 512];
#pragma unroll
    for (int mi = 0; mi < 4; ++mi) af[mi] = *(const bf16x8*)&Sc[aoff + mi * 512];
    if constexpr (STG) {
        gload16(sA,        &Sd[wid * 512]);
        gload16(sA + 4096, &Sd[4096 + wid * 512]);
    }
    __builtin_amdgcn_s_barrier();
    mq<0>(af, bfr, acc);
    __builtin_amdgcn_s_barrier();

    // P1: reads A0(mi4-7); stage B0'; counted wait
#pragma unroll
    for (int mi = 0; mi < 4; ++mi) af[mi] = *(const bf16x8*)&Sc[aoff + (mi + 4) * 512];
    if constexpr (STG) {
        gload16(sB,        &Sd[16384 + wid * 512]);
        gload16(sB + 4096, &Sd[20480 + wid * 512]);
    }
    __builtin_amdgcn_s_barrier();
    mq<4>(af, bfr, acc);
    waitvm<VMW>();
    __builtin_amdgcn_s_barrier();

    // P2: reads B1 + A1(mi0-3); stage A1'
#pragma unroll
    for (int g = 0; g < 4; ++g)    bfr[g] = *(const bf16x8*)&Sc[24576 + boff + g * 512];
#pragma unroll
    for (int mi = 0; mi < 4; ++mi) af[mi] = *(const bf16x8*)&Sc[8192 + aoff + mi * 512];
    if constexpr (STG) {
        gload16(sA + 8192,  &Sd[8192 + wid * 512]);
        gload16(sA + 12288, &Sd[12288 + wid * 512]);
    }
    __builtin_amdgcn_s_barrier();
    mq<0>(af, bfr, acc);
    __builtin_amdgcn_s_barrier();

    // P3: reads A1(mi4-7); stage B1'; counted wait
#pragma unroll
    for (int mi = 0; mi < 4; ++mi) af[mi] = *(const bf16x8*)&Sc[8192 + aoff + (mi + 4) * 512];
    if constexpr (STG) {
        gload16(sB + 8192,  &Sd[24576 + wid * 512]);
        gload16(sB + 12288, &Sd[28672 + wid * 512]);
    }
    __builtin_amdgcn_s_barrier();
    mq<4>(af, bfr, acc);
    waitvm<VMW>();
    __builtin_amdgcn_s_barrier();
}

__global__ __launch_bounds__(NT, 2) void slstm_fused(
    const short* __restrict__ wsA, const short* __restrict__ wsB,
    const float* __restrict__ c_p, const float* __restrict__ n_p,
    const float* __restrict__ m_p, const float* __restrict__ w_b,
    const float* __restrict__ r_b, float* __restrict__ out)
{
    __shared__ __align__(16) short S[2][32768];   // 128 KiB, 2 K-tile slots

    const int t    = threadIdx.x;
    const int lane = t & 63;
    const int wid  = t >> 6;     // 0..7
    const int wm   = wid >> 2;   // 0..1
    const int wn   = wid & 3;    // 0..3
    const int l15  = lane & 15;
    const int l4   = lane >> 4;

    const int b   = (int)blockIdx.x;   // 0..255, persistent (1/CU)
    const int xcd = b & 7;
    const int li  = b >> 3;            // 0..31

    const int sw   = (l4 * 8) ^ (((l15 >> 1) & 3) << 3);
    const int aoff = (wm * 128 + l15) * 32 + sw;   // + mi*512 (unit-internal)
    const int boff = (wn * 64 + l15) * 32 + sw;    // + g*512  (unit-internal)

    float bias[2][4];
#pragma unroll
    for (int p = 0; p < 2; ++p) {
        const int hh = (xcd * 2 + p) * 64 + wn * 16 + l15;
#pragma unroll
        for (int g = 0; g < 4; ++g) bias[p][g] = w_b[g * HD + hh] + r_b[g * HD + hh];
    }

    // prologue: stage tau0/kt0 units in order A0,B0,A1,B1
    const short* a0 = wsA + (size_t)(li * KTILES) * 8192 + t * 8;
    const short* b0 = wsB + (size_t)((xcd * 2) * KTILES) * 8192 + t * 8;
    gload16(a0,         &S[0][wid * 512]);
    gload16(a0 + 4096,  &S[0][4096 + wid * 512]);
    gload16(b0,         &S[0][16384 + wid * 512]);
    gload16(b0 + 4096,  &S[0][20480 + wid * 512]);
    gload16(a0 + 8192,  &S[0][8192 + wid * 512]);
    gload16(a0 + 12288, &S[0][12288 + wid * 512]);
    gload16(b0 + 8192,  &S[0][24576 + wid * 512]);
    gload16(b0 + 12288, &S[0][28672 + wid * 512]);
    asm volatile("s_waitcnt vmcnt(4)" ::: "memory");
    __builtin_amdgcn_s_barrier();

    const short* sA = a0 + 16384;   // stage source = next K-tile
    const short* sB = b0 + 16384;

    const size_t PL = (size_t)NB * HD;

    for (int tau = 0; tau < 4; ++tau) {
        const int bm = li + 32 * (tau >> 1);
        const int bh = xcd * 2 + (tau & 1);
        const int h  = bh * 64 + wn * 16 + l15;

        f32x4 acc[8][4];
#pragma unroll
        for (int g = 0; g < 4; ++g) {
            const float bv = bias[tau & 1][g];
            const f32x4 binit = {bv, bv, bv, bv};
#pragma unroll
            for (int mi = 0; mi < 8; ++mi) acc[mi][g] = binit;
        }

        for (int j = 0; j < 11; ++j) {   // K-tiles 0..21
            ktile<0, true, 4>(sA, sB, S, aoff, boff, wid, acc);
            sA += 16384; sB += 16384;
            ktile<1, true, 4>(sA, sB, S, aoff, boff, wid, acc);
            sA += 16384; sB += 16384;
        }
        // kt22 (slot0): stages kt23
        ktile<0, true, 4>(sA, sB, S, aoff, boff, wid, acc);
        // kt23 (slot1): stages next tile's kt0 (or nothing)
        if (tau < 3) {
            const int nbm = li + 32 * ((tau + 1) >> 1);
            const int nbh = xcd * 2 + ((tau + 1) & 1);
            sA = wsA + (size_t)(nbm * KTILES) * 8192 + t * 8;
            sB = wsB + (size_t)(nbh * KTILES) * 8192 + t * 8;
            ktile<1, true, 4>(sA, sB, S, aoff, boff, wid, acc);
            sA += 16384; sB += 16384;
        } else {
            ktile<1, false, 0>(sA, sB, S, aoff, boff, wid, acc);
        }

        // ---- fused epilogue, native transcendentals ----
#pragma unroll
        for (int mi = 0; mi < 8; ++mi) {
#pragma unroll
            for (int r = 0; r < 4; ++r) {
                const int row = bm * 256 + wm * 128 + mi * 16 + l4 * 4 + r;
                const size_t idx = (size_t)row * HD + h;
                const float ci = acc[mi][0][r];
                const float ig = acc[mi][1][r];
                const float fg = acc[mi][2][r];
                const float og = acc[mi][3][r];
                const float mp  = m_p[idx];
                const float cp  = c_p[idx];
                const float np_ = n_p[idx];
                const float e2 = fexp(-2.0f * fabsf(ci));
                const float zt = (1.0f - e2) * frcp(1.0f + e2);
                const float z  = copysignf(zt, ci);
                const float it_ = fexp(ig);
                const float mt = fmaxf(fg + mp, ig);
                const float sf = fexp(fg + mp - mt);
                const float si = fexp(ig - mt);
                const float ct = sf * cp + it_ * z;
                const float nt = sf * np_ + si;
                const float ot = frcp(1.0f + fexp(-og));
                const float ht = ot * ct * frcp(nt);
                out[idx]          = ht;
                out[PL + idx]     = ct;
                out[2 * PL + idx] = ht;
                out[3 * PL + idx] = nt;
                out[4 * PL + idx] = mt;
            }
        }
    }
}

extern "C" void kernel_launch(void* const* d_in, const int* in_sizes, int n_in,
                              void* d_out, int out_size, void* d_ws, size_t ws_size,
                              hipStream_t stream) {
    const float* x   = (const float*)d_in[0];
    const float* c_p = (const float*)d_in[1];
    const float* h_p = (const float*)d_in[2];
    const float* n_p = (const float*)d_in[3];
    const float* m_p = (const float*)d_in[4];
    const float* w_w = (const float*)d_in[5];
    const float* w_b = (const float*)d_in[6];
    const float* r_w = (const float*)d_in[7];
    const float* r_b = (const float*)d_in[8];
    float* out = (float*)d_out;

    short* wsB = (short*)d_ws;                                         // 12.58 MB
    short* wsA = (short*)((char*)d_ws + (size_t)16 * KTILES * 16384);  // 50.33 MB

    prep_w<<<dim3(16 * KTILES), 256, 0, stream>>>(w_w, r_w, wsB);
    prep_a<<<dim3(64 * KTILES), NT, 0, stream>>>(x, h_p, wsA);
    slstm_fused<<<dim3(256), NT, 0, stream>>>(wsA, wsB, c_p, n_p, m_p, w_b, r_b, out);
}